// Round 6
// baseline (386.875 us; speedup 1.0000x reference)
//
#include <hip/hip_runtime.h>
#include <hip/hip_bf16.h>
#include <cstdint>
#include <cstddef>

#define NN 4096
#define FD 256
#define WPR 64  // 64-bit words per adjacency row

typedef __attribute__((ext_vector_type(8))) unsigned short ushort8v;
typedef __attribute__((ext_vector_type(4))) unsigned short ushort4v;
typedef __attribute__((ext_vector_type(8))) short short8;
typedef __attribute__((ext_vector_type(4))) float float4v;

#define C1 30.0f
#define C2 0.3f    // 0.01 * C1

static __device__ __forceinline__ unsigned short f2bf(float x) {
    union { float f; unsigned int u; } v; v.f = x;
    unsigned int r = v.u + 0x7FFFu + ((v.u >> 16) & 1u);
    return (unsigned short)(r >> 16);
}

static __device__ __forceinline__ short8 as_s8(ushort8v v) {
    union { ushort8v u; short8 s; } x; x.u = v; return x.s;
}

// ---------------- fused setup: pack adj + cvt input + cvt weights + zero f1f2 ----------------
__global__ __launch_bounds__(256) void setup(const int* __restrict__ adj,
                                             const float* __restrict__ input,
                                             const float* __restrict__ W0, const float* __restrict__ W1,
                                             const float* __restrict__ W2, const float* __restrict__ W3,
                                             unsigned long long* __restrict__ bits,
                                             unsigned short* __restrict__ hb,
                                             unsigned short* __restrict__ Wbt,
                                             float* __restrict__ f1f2) {
    const int b = blockIdx.x;
    const int t = threadIdx.x;
    if (b < 4096) {
        const int wave = t >> 6, lane = t & 63;
        const int* arow = adj + (size_t)b * NN;
        #pragma unroll
        for (int it = 0; it < NN / 256; ++it) {
            int j = it * 256 + wave * 64 + lane;
            unsigned long long m = __ballot(arow[j] > 0);
            if (lane == 0) bits[(size_t)b * WPR + (it * 4 + wave)] = m;
        }
        hb[(size_t)b * 256 + t] = f2bf(input[(size_t)b * 256 + t]);
    } else if (b < 5120) {
        int idx = (b - 4096) * 256 + t;
        int mat = idx >> 16;
        int within = idx & 65535;
        int n = within >> 8, k = within & 255;
        const float* W = (mat == 0) ? W0 : (mat == 1) ? W1 : (mat == 2) ? W2 : W3;
        Wbt[idx] = f2bf(W[k * 256 + n]);
    } else {
        #pragma unroll
        for (int i = 0; i < 24; ++i) {
            int pos = i * 1024 + (b - 5120) * 256 + t;
            f1f2[pos] = 0.f;
        }
    }
}

// ---------------- projection GEMM, full-K LDS; epilogue: Cbt/Crow + f1/f2 atomics ----------------
__global__ __launch_bounds__(256) void proj_gemm(const unsigned short* __restrict__ A,
                                                 const unsigned short* __restrict__ Bt,
                                                 const float* __restrict__ av,
                                                 float* __restrict__ f1f2,
                                                 unsigned short* __restrict__ Cbt,
                                                 unsigned short* __restrict__ Crow) {
    const int t = threadIdx.x;
    const int bm = blockIdx.x >> 2, bn = blockIdx.x & 3;
    const int m0 = bm * 64, n0 = bn * 64;
    __shared__ unsigned short As[64 * 264];
    __shared__ unsigned short Bs[64 * 264];
    const int lane = t & 63, wave = t >> 6;
    const int wm = (wave >> 1) * 32, wn = (wave & 1) * 32;
    const int lr = t >> 2, lc0 = (t & 3) * 8;
    #pragma unroll
    for (int i = 0; i < 8; ++i) {
        int col = lc0 + i * 32;
        *(ushort8v*)&As[lr * 264 + col] = *(const ushort8v*)&A[(size_t)(m0 + lr) * 256 + col];
        *(ushort8v*)&Bs[lr * 264 + col] = *(const ushort8v*)&Bt[(size_t)(n0 + lr) * 256 + col];
    }
    __syncthreads();
    float4v acc[2][2] = {{{0.f,0.f,0.f,0.f},{0.f,0.f,0.f,0.f}},{{0.f,0.f,0.f,0.f},{0.f,0.f,0.f,0.f}}};
    #pragma unroll
    for (int kk = 0; kk < 256; kk += 32) {
        const int kc = kk + (lane >> 4) * 8;
        #pragma unroll
        for (int fm = 0; fm < 2; ++fm) {
            short8 a = as_s8(*(const ushort8v*)&As[(wm + fm * 16 + (lane & 15)) * 264 + kc]);
            #pragma unroll
            for (int fn = 0; fn < 2; ++fn) {
                short8 b = as_s8(*(const ushort8v*)&Bs[(wn + fn * 16 + (lane & 15)) * 264 + kc]);
                acc[fm][fn] = __builtin_amdgcn_mfma_f32_16x16x32_bf16(a, b, acc[fm][fn], 0, 0, 0);
            }
        }
    }

    const int rb = wm + (lane >> 4) * 4;
    const int cb = wn + (lane & 15);
    if (Crow) {
        #pragma unroll
        for (int fm = 0; fm < 2; ++fm)
            #pragma unroll
            for (int fn = 0; fn < 2; ++fn)
                #pragma unroll
                for (int r = 0; r < 4; ++r)
                    Crow[(size_t)(m0 + rb + fm * 16 + r) * 256 + n0 + cb + fn * 16] = f2bf(acc[fm][fn][r]);
    }

    if (f1f2) {
        float a1c[2], a2c[2];
        #pragma unroll
        for (int fn = 0; fn < 2; ++fn) {
            a1c[fn] = av[n0 + cb + fn * 16];
            a2c[fn] = av[256 + n0 + cb + fn * 16];
        }
        #pragma unroll
        for (int fm = 0; fm < 2; ++fm)
            #pragma unroll
            for (int r = 0; r < 4; ++r) {
                float s1 = acc[fm][0][r] * a1c[0] + acc[fm][1][r] * a1c[1];
                float s2 = acc[fm][0][r] * a2c[0] + acc[fm][1][r] * a2c[1];
                #pragma unroll
                for (int off = 1; off < 16; off <<= 1) {
                    s1 += __shfl_xor(s1, off, 64);
                    s2 += __shfl_xor(s2, off, 64);
                }
                if ((lane & 15) == 0) {
                    int row = m0 + rb + fm * 16 + r;
                    atomicAdd(&f1f2[row], s1);
                    atomicAdd(&f1f2[4096 + row], s2);
                }
            }
    }

    if (Cbt) {
        unsigned short* T = As;
        __syncthreads();
        #pragma unroll
        for (int fm = 0; fm < 2; ++fm)
            #pragma unroll
            for (int fn = 0; fn < 2; ++fn)
                #pragma unroll
                for (int r = 0; r < 4; ++r)
                    T[(cb + fn * 16) * 72 + rb + fm * 16 + r] = f2bf(acc[fm][fn][r]);
        __syncthreads();
        const int tr = t >> 2;
        #pragma unroll
        for (int i = 0; i < 2; ++i) {
            int tc = (t & 3) * 8 + i * 32;
            *(ushort8v*)&Cbt[(size_t)(n0 + tr) * 4096 + m0 + tc] = *(const ushort8v*)&T[tr * 72 + tc];
        }
    }
}

// ---------------- per-row coefficients + global exp tables ----------------
__global__ __launch_bounds__(256) void rowcoef(const unsigned long long* __restrict__ bits,
                                               const float* __restrict__ f1f2,
                                               float4* __restrict__ rowco,
                                               float2* __restrict__ tab2g) {
    __shared__ float2 tl[4096];
    const int t = threadIdx.x;
    const float* f2p = f1f2 + 4096;
    #pragma unroll
    for (int i = 0; i < 16; ++i) {
        float v = f2p[i * 256 + t];
        float2 pr = make_float2(__expf(v - C1), __expf(0.01f * v - C2));
        tl[i * 256 + t] = pr;
        if (blockIdx.x == 0) tab2g[i * 256 + t] = pr;
    }
    __syncthreads();
    const int lane = t & 63, wave = t >> 6;
    for (int rr = 0; rr < 2; ++rr) {
        const int row = blockIdx.x * 8 + wave * 2 + rr;
        const unsigned long long wl = bits[(size_t)row * WPR + lane];
        const float f1r = f1f2[row];
        const float th = __expf(-f1r - C1);
        float mx = 0.f, S1 = 0.f, S2 = 0.f;
        #pragma unroll 16
        for (int b = 0; b < 64; ++b) {
            unsigned long long w = __shfl(wl, b, 64);
            bool bit = (w >> lane) & 1ULL;
            float2 v = tl[b * 64 + lane];
            float ebm = bit ? v.x : 0.f;
            mx = fmaxf(mx, ebm);
            bool cond = v.x > th;
            S1 += (bit && cond)  ? v.x : 0.f;
            S2 += (bit && !cond) ? v.y : 0.f;
        }
        #pragma unroll
        for (int off = 1; off < 64; off <<= 1) {
            mx = fmaxf(mx, __shfl_xor(mx, off, 64));
            S1 += __shfl_xor(S1, off, 64);
            S2 += __shfl_xor(S2, off, 64);
        }
        if (lane == 0) {
            float M  = C1 + __logf(mx);
            float fm_ = f1r + M;
            float m  = fm_ > 0.f ? fm_ : 0.01f * fm_;    // lrelu
            float alpha = __expf(fminf(f1r + C1 - m, 60.f));
            float gamma = __expf(fminf(0.01f * (f1r + C1) - m, 60.f));
            float inv = 1.0f / (alpha * S1 + gamma * S2);
            rowco[row] = make_float4(alpha * inv, gamma * inv, th, 0.f);
        }
    }
}

// ---------------- attention GEMM, split-K, barrier-free, M=32 tile for occupancy ----------------
__global__ __launch_bounds__(256, 4) void att_flat(const unsigned long long* __restrict__ bits,
                                                   const float4* __restrict__ rowco,
                                                   const float2* __restrict__ tab2,
                                                   const unsigned short* __restrict__ Bt,  // Whbt [256][4096]
                                                   float* __restrict__ part, int kchunk) {
    const int t = threadIdx.x;
    const int bm = blockIdx.x & 127;
    const int ks = blockIdx.x >> 7;
    const int m0 = bm * 32;
    const int k0 = ks * kchunk;
    const int lane = t & 63, wave = t >> 6;
    const int wn = wave * 64;
    const int g = lane >> 4, ml = lane & 15;

    float pA[2], pG[2], thE[2];
    #pragma unroll
    for (int fm = 0; fm < 2; ++fm) {
        float4 rc = rowco[m0 + fm * 16 + ml];
        pA[fm] = rc.x; pG[fm] = rc.y; thE[fm] = rc.z;
    }
    const unsigned long long* bitb = bits + (size_t)(m0 + ml) * WPR;
    const unsigned short* bbase = Bt + (size_t)(wn + ml) * 4096 + g * 8;

    float4v acc[2][4];
    #pragma unroll
    for (int i = 0; i < 2; ++i)
        #pragma unroll
        for (int j = 0; j < 4; ++j) acc[i][j] = (float4v){0.f, 0.f, 0.f, 0.f};

    #pragma unroll 2
    for (int kk = k0; kk < k0 + kchunk; kk += 64) {
        const int word = kk >> 6;
        unsigned long long w64[2];
        #pragma unroll
        for (int fm = 0; fm < 2; ++fm) w64[fm] = bitb[(size_t)(fm * 16) * WPR + word];
        ushort8v breg[4][2];
        #pragma unroll
        for (int fn = 0; fn < 4; ++fn)
            #pragma unroll
            for (int h = 0; h < 2; ++h)
                breg[fn][h] = *(const ushort8v*)&bbase[(size_t)(fn * 16) * 4096 + kk + h * 32];

        #pragma unroll
        for (int h = 0; h < 2; ++h) {
            float tb[8], td[8];
            const float4v* q = (const float4v*)&tab2[kk + h * 32 + g * 8];
            #pragma unroll
            for (int i = 0; i < 4; ++i) {
                float4v v = q[i];
                tb[2 * i] = v[0]; td[2 * i] = v[1]; tb[2 * i + 1] = v[2]; td[2 * i + 1] = v[3];
            }
            short8 afr[2];
            #pragma unroll
            for (int fm = 0; fm < 2; ++fm) {
                unsigned int wh = (unsigned int)(w64[fm] >> (h * 32 + g * 8));
                ushort8v af;
                #pragma unroll
                for (int jj = 0; jj < 4; ++jj) {
                    float e0 = tb[2 * jj], e1 = tb[2 * jj + 1];
                    float p0 = ((wh >> (2 * jj)) & 1u)     ? (e0 > thE[fm] ? pA[fm] * e0 : pG[fm] * td[2 * jj])     : 0.f;
                    float p1 = ((wh >> (2 * jj + 1)) & 1u) ? (e1 > thE[fm] ? pA[fm] * e1 : pG[fm] * td[2 * jj + 1]) : 0.f;
                    union { __hip_bfloat162 b2; unsigned short us[2]; } cv;
                    cv.b2 = __float22bfloat162_rn(make_float2(p0, p1));
                    af[2 * jj] = cv.us[0]; af[2 * jj + 1] = cv.us[1];
                }
                afr[fm] = as_s8(af);
            }
            #pragma unroll
            for (int fm = 0; fm < 2; ++fm)
                #pragma unroll
                for (int fn = 0; fn < 4; ++fn)
                    acc[fm][fn] = __builtin_amdgcn_mfma_f32_16x16x32_bf16(afr[fm], as_s8(breg[fn][h]), acc[fm][fn], 0, 0, 0);
        }
    }

    const int rb = g * 4;
    const int cb = wn + ml;
    float* pbase = part + ((size_t)ks << 20);
    #pragma unroll
    for (int fm = 0; fm < 2; ++fm)
        #pragma unroll
        for (int fn = 0; fn < 4; ++fn)
            #pragma unroll
            for (int r = 0; r < 4; ++r)
                pbase[(size_t)(m0 + rb + fm * 16 + r) * 256 + cb + fn * 16] = acc[fm][fn][r];
}

// ---------------- reduce split-K partials + ELU (P already normalized) ----------------
__global__ __launch_bounds__(256) void att_reduce(const float* __restrict__ part,
                                                  float* __restrict__ outf,
                                                  unsigned short* __restrict__ hrow, int nsplit) {
    const int idx = (blockIdx.x * 256 + threadIdx.x) * 4;
    float4v s = *(const float4v*)&part[idx];
    for (int sp = 1; sp < nsplit; ++sp)
        s += *(const float4v*)&part[((size_t)sp << 20) + idx];
    float4v v;
    ushort4v hb;
    #pragma unroll
    for (int j = 0; j < 4; ++j) {
        float x = s[j];
        x = x > 0.f ? x : (__expf(x) - 1.f);
        v[j] = x;
        hb[j] = f2bf(x);
    }
    if (outf) *(float4v*)&outf[idx] = v;
    *(ushort4v*)&hrow[idx] = hb;
}

extern "C" void kernel_launch(void* const* d_in, const int* in_sizes, int n_in,
                              void* d_out, int out_size, void* d_ws, size_t ws_size,
                              hipStream_t stream) {
    const float* input = (const float*)d_in[0];
    const int*   adj   = (const int*)d_in[1];
    const float* W0    = (const float*)d_in[2];
    const float* W1    = (const float*)d_in[3];
    const float* a1    = (const float*)d_in[4];
    const float* W2    = (const float*)d_in[5];
    const float* a2    = (const float*)d_in[6];
    const float* W3    = (const float*)d_in[7];
    const float* a3    = (const float*)d_in[8];
    float* out = (float*)d_out;
    char* ws = (char*)d_ws;

    unsigned long long* bits = (unsigned long long*)(ws);                 // 2 MB
    unsigned short* h0   = (unsigned short*)(ws + (2u << 20));            // 2 MB
    unsigned short* h1   = (unsigned short*)(ws + (4u << 20));            // 2 MB
    unsigned short* Whbt = (unsigned short*)(ws + (6u << 20));            // 2 MB
    unsigned short* Wbt  = (unsigned short*)(ws + (8u << 20));            // 512 KB
    float*  f1f2  = (float*)(ws + (9u << 20));                            // 3 layers x 32 KB
    float4* rowco = (float4*)(ws + (10u << 20));                          // 64 KB
    float2* tab2  = (float2*)(ws + (10u << 20) + (256u << 10));           // 32 KB
    float*  part  = (float*)(ws + (13u << 20));                           // 4 MB * SPLIT

    const size_t base = 13u << 20;
    int SPLIT = 16;
    while (SPLIT > 1 && base + (size_t)SPLIT * (4u << 20) > ws_size) SPLIT >>= 1;
    const int kchunk = NN / SPLIT;

    float* f1f2_l[3] = { f1f2, f1f2 + 8192, f1f2 + 16384 };

    setup<<<5124, 256, 0, stream>>>(adj, input, W0, W1, W2, W3, bits, h0, Wbt, f1f2);

    // h = input @ W0 -> h1
    proj_gemm<<<256, 256, 0, stream>>>(h0, Wbt + 0 * 65536, nullptr, nullptr, nullptr, h1);

    // layer 1
    proj_gemm<<<256, 256, 0, stream>>>(h1, Wbt + 1 * 65536, a1, f1f2_l[0], Whbt, nullptr);
    rowcoef<<<512, 256, 0, stream>>>(bits, f1f2_l[0], rowco, tab2);
    att_flat<<<128 * SPLIT, 256, 0, stream>>>(bits, rowco, tab2, Whbt, part, kchunk);
    att_reduce<<<1024, 256, 0, stream>>>(part, nullptr, h0, SPLIT);

    // layer 2
    proj_gemm<<<256, 256, 0, stream>>>(h0, Wbt + 2 * 65536, a2, f1f2_l[1], Whbt, nullptr);
    rowcoef<<<512, 256, 0, stream>>>(bits, f1f2_l[1], rowco, tab2);
    att_flat<<<128 * SPLIT, 256, 0, stream>>>(bits, rowco, tab2, Whbt, part, kchunk);
    att_reduce<<<1024, 256, 0, stream>>>(part, nullptr, h1, SPLIT);

    // layer 3
    proj_gemm<<<256, 256, 0, stream>>>(h1, Wbt + 3 * 65536, a3, f1f2_l[2], Whbt, nullptr);
    rowcoef<<<512, 256, 0, stream>>>(bits, f1f2_l[2], rowco, tab2);
    att_flat<<<128 * SPLIT, 256, 0, stream>>>(bits, rowco, tab2, Whbt, part, kchunk);
    att_reduce<<<1024, 256, 0, stream>>>(part, out, h0, SPLIT);
}

// Round 7
// 328.416 us; speedup vs baseline: 1.1780x; 1.1780x over previous
//
#include <hip/hip_runtime.h>
#include <hip/hip_bf16.h>
#include <cstdint>
#include <cstddef>

#define NN 4096
#define FD 256
#define WPR 64  // 64-bit words per adjacency row

typedef __attribute__((ext_vector_type(8))) unsigned short ushort8v;
typedef __attribute__((ext_vector_type(4))) unsigned short ushort4v;
typedef __attribute__((ext_vector_type(8))) short short8;
typedef __attribute__((ext_vector_type(4))) float float4v;

#define C1 30.0f
#define C2 0.3f    // 0.01 * C1

static __device__ __forceinline__ unsigned short f2bf(float x) {
    union { float f; unsigned int u; } v; v.f = x;
    unsigned int r = v.u + 0x7FFFu + ((v.u >> 16) & 1u);
    return (unsigned short)(r >> 16);
}

static __device__ __forceinline__ short8 as_s8(ushort8v v) {
    union { ushort8v u; short8 s; } x; x.u = v; return x.s;
}

// ---------------- fused setup: pack adj + cvt input + cvt weights + zero f1f2 ----------------
__global__ __launch_bounds__(256) void setup(const int* __restrict__ adj,
                                             const float* __restrict__ input,
                                             const float* __restrict__ W0, const float* __restrict__ W1,
                                             const float* __restrict__ W2, const float* __restrict__ W3,
                                             unsigned long long* __restrict__ bits,
                                             unsigned short* __restrict__ hb,
                                             unsigned short* __restrict__ Wbt,
                                             float* __restrict__ f1f2) {
    const int b = blockIdx.x;
    const int t = threadIdx.x;
    if (b < 4096) {
        const int wave = t >> 6, lane = t & 63;
        const int* arow = adj + (size_t)b * NN;
        #pragma unroll
        for (int it = 0; it < NN / 256; ++it) {
            int j = it * 256 + wave * 64 + lane;
            unsigned long long m = __ballot(arow[j] > 0);
            if (lane == 0) bits[(size_t)b * WPR + (it * 4 + wave)] = m;
        }
        hb[(size_t)b * 256 + t] = f2bf(input[(size_t)b * 256 + t]);
    } else if (b < 5120) {
        int idx = (b - 4096) * 256 + t;
        int mat = idx >> 16;
        int within = idx & 65535;
        int n = within >> 8, k = within & 255;
        const float* W = (mat == 0) ? W0 : (mat == 1) ? W1 : (mat == 2) ? W2 : W3;
        Wbt[idx] = f2bf(W[k * 256 + n]);
    } else {
        #pragma unroll
        for (int i = 0; i < 24; ++i) {
            int pos = i * 1024 + (b - 5120) * 256 + t;
            f1f2[pos] = 0.f;
        }
    }
}

// ---------------- projection GEMM, full-K LDS; epilogue: Cbt/Crow + f1/f2 atomics ----------------
__global__ __launch_bounds__(256) void proj_gemm(const unsigned short* __restrict__ A,
                                                 const unsigned short* __restrict__ Bt,
                                                 const float* __restrict__ av,
                                                 float* __restrict__ f1f2,
                                                 unsigned short* __restrict__ Cbt,
                                                 unsigned short* __restrict__ Crow) {
    const int t = threadIdx.x;
    const int bm = blockIdx.x >> 2, bn = blockIdx.x & 3;
    const int m0 = bm * 64, n0 = bn * 64;
    __shared__ unsigned short As[64 * 264];
    __shared__ unsigned short Bs[64 * 264];
    const int lane = t & 63, wave = t >> 6;
    const int wm = (wave >> 1) * 32, wn = (wave & 1) * 32;
    const int lr = t >> 2, lc0 = (t & 3) * 8;
    #pragma unroll
    for (int i = 0; i < 8; ++i) {
        int col = lc0 + i * 32;
        *(ushort8v*)&As[lr * 264 + col] = *(const ushort8v*)&A[(size_t)(m0 + lr) * 256 + col];
        *(ushort8v*)&Bs[lr * 264 + col] = *(const ushort8v*)&Bt[(size_t)(n0 + lr) * 256 + col];
    }
    __syncthreads();
    float4v acc[2][2] = {{{0.f,0.f,0.f,0.f},{0.f,0.f,0.f,0.f}},{{0.f,0.f,0.f,0.f},{0.f,0.f,0.f,0.f}}};
    #pragma unroll
    for (int kk = 0; kk < 256; kk += 32) {
        const int kc = kk + (lane >> 4) * 8;
        #pragma unroll
        for (int fm = 0; fm < 2; ++fm) {
            short8 a = as_s8(*(const ushort8v*)&As[(wm + fm * 16 + (lane & 15)) * 264 + kc]);
            #pragma unroll
            for (int fn = 0; fn < 2; ++fn) {
                short8 b = as_s8(*(const ushort8v*)&Bs[(wn + fn * 16 + (lane & 15)) * 264 + kc]);
                acc[fm][fn] = __builtin_amdgcn_mfma_f32_16x16x32_bf16(a, b, acc[fm][fn], 0, 0, 0);
            }
        }
    }

    const int rb = wm + (lane >> 4) * 4;
    const int cb = wn + (lane & 15);
    if (Crow) {
        #pragma unroll
        for (int fm = 0; fm < 2; ++fm)
            #pragma unroll
            for (int fn = 0; fn < 2; ++fn)
                #pragma unroll
                for (int r = 0; r < 4; ++r)
                    Crow[(size_t)(m0 + rb + fm * 16 + r) * 256 + n0 + cb + fn * 16] = f2bf(acc[fm][fn][r]);
    }

    if (f1f2) {
        float a1c[2], a2c[2];
        #pragma unroll
        for (int fn = 0; fn < 2; ++fn) {
            a1c[fn] = av[n0 + cb + fn * 16];
            a2c[fn] = av[256 + n0 + cb + fn * 16];
        }
        #pragma unroll
        for (int fm = 0; fm < 2; ++fm)
            #pragma unroll
            for (int r = 0; r < 4; ++r) {
                float s1 = acc[fm][0][r] * a1c[0] + acc[fm][1][r] * a1c[1];
                float s2 = acc[fm][0][r] * a2c[0] + acc[fm][1][r] * a2c[1];
                #pragma unroll
                for (int off = 1; off < 16; off <<= 1) {
                    s1 += __shfl_xor(s1, off, 64);
                    s2 += __shfl_xor(s2, off, 64);
                }
                if ((lane & 15) == 0) {
                    int row = m0 + rb + fm * 16 + r;
                    atomicAdd(&f1f2[row], s1);
                    atomicAdd(&f1f2[4096 + row], s2);
                }
            }
    }

    if (Cbt) {
        unsigned short* T = As;
        __syncthreads();
        #pragma unroll
        for (int fm = 0; fm < 2; ++fm)
            #pragma unroll
            for (int fn = 0; fn < 2; ++fn)
                #pragma unroll
                for (int r = 0; r < 4; ++r)
                    T[(cb + fn * 16) * 72 + rb + fm * 16 + r] = f2bf(acc[fm][fn][r]);
        __syncthreads();
        const int tr = t >> 2;
        #pragma unroll
        for (int i = 0; i < 2; ++i) {
            int tc = (t & 3) * 8 + i * 32;
            *(ushort8v*)&Cbt[(size_t)(n0 + tr) * 4096 + m0 + tc] = *(const ushort8v*)&T[tr * 72 + tc];
        }
    }
}

// ---------------- per-row coefficients + global exp tables ----------------
__global__ __launch_bounds__(256) void rowcoef(const unsigned long long* __restrict__ bits,
                                               const float* __restrict__ f1f2,
                                               float4* __restrict__ rowco,
                                               float2* __restrict__ tab2g) {
    __shared__ float2 tl[4096];
    const int t = threadIdx.x;
    const float* f2p = f1f2 + 4096;
    #pragma unroll
    for (int i = 0; i < 16; ++i) {
        float v = f2p[i * 256 + t];
        float2 pr = make_float2(__expf(v - C1), __expf(0.01f * v - C2));
        tl[i * 256 + t] = pr;
        if (blockIdx.x == 0) tab2g[i * 256 + t] = pr;
    }
    __syncthreads();
    const int lane = t & 63, wave = t >> 6;
    for (int rr = 0; rr < 2; ++rr) {
        const int row = blockIdx.x * 8 + wave * 2 + rr;
        const unsigned long long wl = bits[(size_t)row * WPR + lane];
        const float f1r = f1f2[row];
        const float th = __expf(-f1r - C1);
        float mx = 0.f, S1 = 0.f, S2 = 0.f;
        #pragma unroll 16
        for (int b = 0; b < 64; ++b) {
            unsigned long long w = __shfl(wl, b, 64);
            bool bit = (w >> lane) & 1ULL;
            float2 v = tl[b * 64 + lane];
            float ebm = bit ? v.x : 0.f;
            mx = fmaxf(mx, ebm);
            bool cond = v.x > th;
            S1 += (bit && cond)  ? v.x : 0.f;
            S2 += (bit && !cond) ? v.y : 0.f;
        }
        #pragma unroll
        for (int off = 1; off < 64; off <<= 1) {
            mx = fmaxf(mx, __shfl_xor(mx, off, 64));
            S1 += __shfl_xor(S1, off, 64);
            S2 += __shfl_xor(S2, off, 64);
        }
        if (lane == 0) {
            float M  = C1 + __logf(mx);
            float fm_ = f1r + M;
            float m  = fm_ > 0.f ? fm_ : 0.01f * fm_;    // lrelu
            float alpha = __expf(fminf(f1r + C1 - m, 60.f));
            float gamma = __expf(fminf(0.01f * (f1r + C1) - m, 60.f));
            float inv = 1.0f / (alpha * S1 + gamma * S2);
            rowco[row] = make_float4(alpha * inv, gamma * inv, th, 0.f);
        }
    }
}

// ---------------- attention GEMM: m97-structure 128x128 tile, BK=32, split-K ----------------
// A (normalized P) generated into LDS (16 elems/thread/step); B staged into LDS; 16 MFMA/wave/step.
__global__ __launch_bounds__(256, 2) void att_gemm(const unsigned long long* __restrict__ bits,
                                                   const float4* __restrict__ rowco,
                                                   const float2* __restrict__ tab2,
                                                   const unsigned short* __restrict__ Bt,  // Whbt [256][4096]
                                                   float* __restrict__ part, int kchunk) {
    const int t = threadIdx.x;
    const int bm = blockIdx.x & 31;
    const int bn = (blockIdx.x >> 5) & 1;
    const int ks = blockIdx.x >> 6;
    const int m0 = bm * 128, n0 = bn * 128;
    const int k0 = ks * kchunk;
    __shared__ unsigned short As[128 * 40];   // 10.2 KB
    __shared__ unsigned short Bs[128 * 40];   // 10.2 KB
    const int lane = t & 63, wave = t >> 6;
    const int wm = (wave >> 1) * 64, wn = (wave & 1) * 64;
    const int g = lane >> 4, ml = lane & 15;
    const int r = t >> 1, kh = (t & 1) * 16;   // staging row / k-half

    const float4 rc = rowco[m0 + r];
    const float pA = rc.x, pG = rc.y, th = rc.z;
    const unsigned long long* brow = bits + (size_t)(m0 + r) * WPR;
    const unsigned short* bsrc = Bt + (size_t)(n0 + r) * 4096 + kh;

    float4v acc[4][4];
    #pragma unroll
    for (int i = 0; i < 4; ++i)
        #pragma unroll
        for (int j = 0; j < 4; ++j) acc[i][j] = (float4v){0.f, 0.f, 0.f, 0.f};

    for (int kk = k0; kk < k0 + kchunk; kk += 32) {
        // B global loads first; latency hides under A-gen VALU
        ushort8v b0 = *(const ushort8v*)&bsrc[kk];
        ushort8v b1 = *(const ushort8v*)&bsrc[kk + 8];
        // A-gen: 16 normalized P elems for row r, k in [kk+kh, kk+kh+16)
        unsigned int wb = (unsigned int)((brow[kk >> 6] >> ((kk & 63) + kh)) & 0xFFFFu);
        const float4v* q = (const float4v*)&tab2[kk + kh];
        ushort8v p0, p1;
        #pragma unroll
        for (int jj = 0; jj < 8; ++jj) {
            float4v v = q[jj];        // (eb0, ed0, eb1, ed1)
            float x0 = ((wb >> (2 * jj)) & 1u)     ? (v[0] > th ? pA * v[0] : pG * v[1]) : 0.f;
            float x1 = ((wb >> (2 * jj + 1)) & 1u) ? (v[2] > th ? pA * v[2] : pG * v[3]) : 0.f;
            union { __hip_bfloat162 b2; unsigned int u; } cv;
            cv.b2 = __float22bfloat162_rn(make_float2(x0, x1));
            if (jj < 4) ((unsigned int*)&p0)[jj] = cv.u;
            else        ((unsigned int*)&p1)[jj - 4] = cv.u;
        }
        *(ushort8v*)&As[r * 40 + kh]     = p0;
        *(ushort8v*)&As[r * 40 + kh + 8] = p1;
        *(ushort8v*)&Bs[r * 40 + kh]     = b0;
        *(ushort8v*)&Bs[r * 40 + kh + 8] = b1;
        __syncthreads();
        const int kc = g * 8;
        short8 a[4], b[4];
        #pragma unroll
        for (int fm = 0; fm < 4; ++fm)
            a[fm] = as_s8(*(const ushort8v*)&As[(wm + fm * 16 + ml) * 40 + kc]);
        #pragma unroll
        for (int fn = 0; fn < 4; ++fn)
            b[fn] = as_s8(*(const ushort8v*)&Bs[(wn + fn * 16 + ml) * 40 + kc]);
        #pragma unroll
        for (int fm = 0; fm < 4; ++fm)
            #pragma unroll
            for (int fn = 0; fn < 4; ++fn)
                acc[fm][fn] = __builtin_amdgcn_mfma_f32_16x16x32_bf16(a[fm], b[fn], acc[fm][fn], 0, 0, 0);
        __syncthreads();
    }

    float* pbase = part + ((size_t)ks << 20);
    #pragma unroll
    for (int fm = 0; fm < 4; ++fm)
        #pragma unroll
        for (int fn = 0; fn < 4; ++fn)
            #pragma unroll
            for (int rr = 0; rr < 4; ++rr)
                pbase[(size_t)(m0 + wm + fm * 16 + g * 4 + rr) * 256 + n0 + wn + fn * 16 + ml] = acc[fm][fn][rr];
}

// ---------------- reduce split-K partials + ELU (P already normalized) ----------------
__global__ __launch_bounds__(256) void att_reduce(const float* __restrict__ part,
                                                  float* __restrict__ outf,
                                                  unsigned short* __restrict__ hrow, int nsplit) {
    const int idx = (blockIdx.x * 256 + threadIdx.x) * 4;
    float4v s = *(const float4v*)&part[idx];
    for (int sp = 1; sp < nsplit; ++sp)
        s += *(const float4v*)&part[((size_t)sp << 20) + idx];
    float4v v;
    ushort4v hb;
    #pragma unroll
    for (int j = 0; j < 4; ++j) {
        float x = s[j];
        x = x > 0.f ? x : (__expf(x) - 1.f);
        v[j] = x;
        hb[j] = f2bf(x);
    }
    if (outf) *(float4v*)&outf[idx] = v;
    *(ushort4v*)&hrow[idx] = hb;
}

extern "C" void kernel_launch(void* const* d_in, const int* in_sizes, int n_in,
                              void* d_out, int out_size, void* d_ws, size_t ws_size,
                              hipStream_t stream) {
    const float* input = (const float*)d_in[0];
    const int*   adj   = (const int*)d_in[1];
    const float* W0    = (const float*)d_in[2];
    const float* W1    = (const float*)d_in[3];
    const float* a1    = (const float*)d_in[4];
    const float* W2    = (const float*)d_in[5];
    const float* a2    = (const float*)d_in[6];
    const float* W3    = (const float*)d_in[7];
    const float* a3    = (const float*)d_in[8];
    float* out = (float*)d_out;
    char* ws = (char*)d_ws;

    unsigned long long* bits = (unsigned long long*)(ws);                 // 2 MB
    unsigned short* h0   = (unsigned short*)(ws + (2u << 20));            // 2 MB
    unsigned short* h1   = (unsigned short*)(ws + (4u << 20));            // 2 MB
    unsigned short* Whbt = (unsigned short*)(ws + (6u << 20));            // 2 MB
    unsigned short* Wbt  = (unsigned short*)(ws + (8u << 20));            // 512 KB
    float*  f1f2  = (float*)(ws + (9u << 20));                            // 3 layers x 32 KB
    float4* rowco = (float4*)(ws + (10u << 20));                          // 64 KB
    float2* tab2  = (float2*)(ws + (10u << 20) + (256u << 10));           // 32 KB
    float*  part  = (float*)(ws + (13u << 20));                           // 4 MB * SPLIT

    const size_t base = 13u << 20;
    int SPLIT = 8;
    while (SPLIT > 1 && base + (size_t)SPLIT * (4u << 20) > ws_size) SPLIT >>= 1;
    const int kchunk = NN / SPLIT;

    float* f1f2_l[3] = { f1f2, f1f2 + 8192, f1f2 + 16384 };

    setup<<<5124, 256, 0, stream>>>(adj, input, W0, W1, W2, W3, bits, h0, Wbt, f1f2);

    // h = input @ W0 -> h1
    proj_gemm<<<256, 256, 0, stream>>>(h0, Wbt + 0 * 65536, nullptr, nullptr, nullptr, h1);

    // layer 1
    proj_gemm<<<256, 256, 0, stream>>>(h1, Wbt + 1 * 65536, a1, f1f2_l[0], Whbt, nullptr);
    rowcoef<<<512, 256, 0, stream>>>(bits, f1f2_l[0], rowco, tab2);
    att_gemm<<<64 * SPLIT, 256, 0, stream>>>(bits, rowco, tab2, Whbt, part, kchunk);
    att_reduce<<<1024, 256, 0, stream>>>(part, nullptr, h0, SPLIT);

    // layer 2
    proj_gemm<<<256, 256, 0, stream>>>(h0, Wbt + 2 * 65536, a2, f1f2_l[1], Whbt, nullptr);
    rowcoef<<<512, 256, 0, stream>>>(bits, f1f2_l[1], rowco, tab2);
    att_gemm<<<64 * SPLIT, 256, 0, stream>>>(bits, rowco, tab2, Whbt, part, kchunk);
    att_reduce<<<1024, 256, 0, stream>>>(part, nullptr, h1, SPLIT);

    // layer 3
    proj_gemm<<<256, 256, 0, stream>>>(h1, Wbt + 3 * 65536, a3, f1f2_l[2], Whbt, nullptr);
    rowcoef<<<512, 256, 0, stream>>>(bits, f1f2_l[2], rowco, tab2);
    att_gemm<<<64 * SPLIT, 256, 0, stream>>>(bits, rowco, tab2, Whbt, part, kchunk);
    att_reduce<<<1024, 256, 0, stream>>>(part, out, h0, SPLIT);
}

// Round 8
// 290.028 us; speedup vs baseline: 1.3339x; 1.1324x over previous
//
#include <hip/hip_runtime.h>
#include <hip/hip_bf16.h>
#include <hip/hip_fp16.h>
#include <cstdint>
#include <cstddef>

#define NN 4096
#define FD 256
#define WPR 64  // 64-bit words per adjacency row

typedef __attribute__((ext_vector_type(8))) unsigned short ushort8v;
typedef __attribute__((ext_vector_type(4))) unsigned short ushort4v;
typedef __attribute__((ext_vector_type(8))) short short8;
typedef __attribute__((ext_vector_type(4))) float float4v;

#define C1 30.0f
#define C2 0.3f    // 0.01 * C1

static __device__ __forceinline__ unsigned short f2bf(float x) {
    union { float f; unsigned int u; } v; v.f = x;
    unsigned int r = v.u + 0x7FFFu + ((v.u >> 16) & 1u);
    return (unsigned short)(r >> 16);
}

static __device__ __forceinline__ short8 as_s8(ushort8v v) {
    union { ushort8v u; short8 s; } x; x.u = v; return x.s;
}

// ---------------- fused setup: pack adj + cvt input + cvt weights + zero f1f2 ----------------
__global__ __launch_bounds__(256) void setup(const int* __restrict__ adj,
                                             const float* __restrict__ input,
                                             const float* __restrict__ W0, const float* __restrict__ W1,
                                             const float* __restrict__ W2, const float* __restrict__ W3,
                                             unsigned long long* __restrict__ bits,
                                             unsigned short* __restrict__ hb,
                                             unsigned short* __restrict__ Wbt,
                                             float* __restrict__ f1f2) {
    const int b = blockIdx.x;
    const int t = threadIdx.x;
    if (b < 4096) {
        const int wave = t >> 6, lane = t & 63;
        const int* arow = adj + (size_t)b * NN;
        #pragma unroll
        for (int it = 0; it < NN / 256; ++it) {
            int j = it * 256 + wave * 64 + lane;
            unsigned long long m = __ballot(arow[j] > 0);
            if (lane == 0) bits[(size_t)b * WPR + (it * 4 + wave)] = m;
        }
        hb[(size_t)b * 256 + t] = f2bf(input[(size_t)b * 256 + t]);
    } else if (b < 5120) {
        int idx = (b - 4096) * 256 + t;
        int mat = idx >> 16;
        int within = idx & 65535;
        int n = within >> 8, k = within & 255;
        const float* W = (mat == 0) ? W0 : (mat == 1) ? W1 : (mat == 2) ? W2 : W3;
        Wbt[idx] = f2bf(W[k * 256 + n]);
    } else {
        #pragma unroll
        for (int i = 0; i < 24; ++i) {
            int pos = i * 1024 + (b - 5120) * 256 + t;
            f1f2[pos] = 0.f;
        }
    }
}

// ---------------- projection GEMM, full-K LDS; epilogue: Cbt/Crow + f1/f2 atomics ----------------
__global__ __launch_bounds__(256) void proj_gemm(const unsigned short* __restrict__ A,
                                                 const unsigned short* __restrict__ Bt,
                                                 const float* __restrict__ av,
                                                 float* __restrict__ f1f2,
                                                 unsigned short* __restrict__ Cbt,
                                                 unsigned short* __restrict__ Crow) {
    const int t = threadIdx.x;
    const int bm = blockIdx.x >> 2, bn = blockIdx.x & 3;
    const int m0 = bm * 64, n0 = bn * 64;
    __shared__ unsigned short As[64 * 264];
    __shared__ unsigned short Bs[64 * 264];
    const int lane = t & 63, wave = t >> 6;
    const int wm = (wave >> 1) * 32, wn = (wave & 1) * 32;
    const int lr = t >> 2, lc0 = (t & 3) * 8;
    #pragma unroll
    for (int i = 0; i < 8; ++i) {
        int col = lc0 + i * 32;
        *(ushort8v*)&As[lr * 264 + col] = *(const ushort8v*)&A[(size_t)(m0 + lr) * 256 + col];
        *(ushort8v*)&Bs[lr * 264 + col] = *(const ushort8v*)&Bt[(size_t)(n0 + lr) * 256 + col];
    }
    __syncthreads();
    float4v acc[2][2] = {{{0.f,0.f,0.f,0.f},{0.f,0.f,0.f,0.f}},{{0.f,0.f,0.f,0.f},{0.f,0.f,0.f,0.f}}};
    #pragma unroll
    for (int kk = 0; kk < 256; kk += 32) {
        const int kc = kk + (lane >> 4) * 8;
        #pragma unroll
        for (int fm = 0; fm < 2; ++fm) {
            short8 a = as_s8(*(const ushort8v*)&As[(wm + fm * 16 + (lane & 15)) * 264 + kc]);
            #pragma unroll
            for (int fn = 0; fn < 2; ++fn) {
                short8 b = as_s8(*(const ushort8v*)&Bs[(wn + fn * 16 + (lane & 15)) * 264 + kc]);
                acc[fm][fn] = __builtin_amdgcn_mfma_f32_16x16x32_bf16(a, b, acc[fm][fn], 0, 0, 0);
            }
        }
    }

    const int rb = wm + (lane >> 4) * 4;
    const int cb = wn + (lane & 15);
    if (Crow) {
        #pragma unroll
        for (int fm = 0; fm < 2; ++fm)
            #pragma unroll
            for (int fn = 0; fn < 2; ++fn)
                #pragma unroll
                for (int r = 0; r < 4; ++r)
                    Crow[(size_t)(m0 + rb + fm * 16 + r) * 256 + n0 + cb + fn * 16] = f2bf(acc[fm][fn][r]);
    }

    if (f1f2) {
        float a1c[2], a2c[2];
        #pragma unroll
        for (int fn = 0; fn < 2; ++fn) {
            a1c[fn] = av[n0 + cb + fn * 16];
            a2c[fn] = av[256 + n0 + cb + fn * 16];
        }
        #pragma unroll
        for (int fm = 0; fm < 2; ++fm)
            #pragma unroll
            for (int r = 0; r < 4; ++r) {
                float s1 = acc[fm][0][r] * a1c[0] + acc[fm][1][r] * a1c[1];
                float s2 = acc[fm][0][r] * a2c[0] + acc[fm][1][r] * a2c[1];
                #pragma unroll
                for (int off = 1; off < 16; off <<= 1) {
                    s1 += __shfl_xor(s1, off, 64);
                    s2 += __shfl_xor(s2, off, 64);
                }
                if ((lane & 15) == 0) {
                    int row = m0 + rb + fm * 16 + r;
                    atomicAdd(&f1f2[row], s1);
                    atomicAdd(&f1f2[4096 + row], s2);
                }
            }
    }

    if (Cbt) {
        unsigned short* T = As;
        __syncthreads();
        #pragma unroll
        for (int fm = 0; fm < 2; ++fm)
            #pragma unroll
            for (int fn = 0; fn < 2; ++fn)
                #pragma unroll
                for (int r = 0; r < 4; ++r)
                    T[(cb + fn * 16) * 72 + rb + fm * 16 + r] = f2bf(acc[fm][fn][r]);
        __syncthreads();
        const int tr = t >> 2;
        #pragma unroll
        for (int i = 0; i < 2; ++i) {
            int tc = (t & 3) * 8 + i * 32;
            *(ushort8v*)&Cbt[(size_t)(n0 + tr) * 4096 + m0 + tc] = *(const ushort8v*)&T[tr * 72 + tc];
        }
    }
}

// ---------------- per-row coefficients + global exp tables ----------------
__global__ __launch_bounds__(256) void rowcoef(const unsigned long long* __restrict__ bits,
                                               const float* __restrict__ f1f2,
                                               float4* __restrict__ rowco,
                                               float2* __restrict__ tab2g) {
    __shared__ float2 tl[4096];
    const int t = threadIdx.x;
    const float* f2p = f1f2 + 4096;
    #pragma unroll
    for (int i = 0; i < 16; ++i) {
        float v = f2p[i * 256 + t];
        float2 pr = make_float2(__expf(v - C1), __expf(0.01f * v - C2));
        tl[i * 256 + t] = pr;
        if (blockIdx.x == 0) tab2g[i * 256 + t] = pr;
    }
    __syncthreads();
    const int lane = t & 63, wave = t >> 6;
    for (int rr = 0; rr < 2; ++rr) {
        const int row = blockIdx.x * 8 + wave * 2 + rr;
        const unsigned long long wl = bits[(size_t)row * WPR + lane];
        const float f1r = f1f2[row];
        const float th = __expf(-f1r - C1);
        float mx = 0.f, S1 = 0.f, S2 = 0.f;
        #pragma unroll 16
        for (int b = 0; b < 64; ++b) {
            unsigned long long w = __shfl(wl, b, 64);
            bool bit = (w >> lane) & 1ULL;
            float2 v = tl[b * 64 + lane];
            float ebm = bit ? v.x : 0.f;
            mx = fmaxf(mx, ebm);
            bool cond = v.x > th;
            S1 += (bit && cond)  ? v.x : 0.f;
            S2 += (bit && !cond) ? v.y : 0.f;
        }
        #pragma unroll
        for (int off = 1; off < 64; off <<= 1) {
            mx = fmaxf(mx, __shfl_xor(mx, off, 64));
            S1 += __shfl_xor(S1, off, 64);
            S2 += __shfl_xor(S2, off, 64);
        }
        if (lane == 0) {
            float M  = C1 + __logf(mx);
            float fm_ = f1r + M;
            float m  = fm_ > 0.f ? fm_ : 0.01f * fm_;    // lrelu
            float alpha = __expf(fminf(f1r + C1 - m, 60.f));
            float gamma = __expf(fminf(0.01f * (f1r + C1) - m, 60.f));
            float inv = 1.0f / (alpha * S1 + gamma * S2);
            rowco[row] = make_float4(alpha * inv, gamma * inv, th, 0.f);
        }
    }
}

// ---------------- attention GEMM v8: 128x128 tile, waves stripe M (A private in regs),
// B double-buffered in LDS with ONE barrier per K-step, split-K, fp16 partials ----------------
__global__ __launch_bounds__(256, 4) void att_gemm(const unsigned long long* __restrict__ bits,
                                                   const float4* __restrict__ rowco,
                                                   const float* __restrict__ tab2f,
                                                   const unsigned short* __restrict__ Bt,  // Whbt [256][4096]
                                                   unsigned short* __restrict__ parth, int kchunk) {
    const int t = threadIdx.x;
    const int bm = blockIdx.x & 31;
    const int bn = (blockIdx.x >> 5) & 1;
    const int ks = blockIdx.x >> 6;
    const int m0 = bm * 128, n0 = bn * 128;
    const int k0 = ks * kchunk;
    __shared__ unsigned short Bs[2][128 * 40];   // 2 x 10.25 KB
    const int lane = t & 63, wave = t >> 6;
    const int g = lane >> 4, ml = lane & 15;

    // staging assignment: thread t stages B row srow, k-half skh
    const int srow = t >> 1, skh = (t & 1) * 16;
    const unsigned short* bsrc = Bt + (size_t)(n0 + srow) * 4096 + skh;

    // per-wave A rows (wave stripes M): rows m0 + 32*wave + fm*16 + ml
    float pA[2], pG[2], th[2];
    const unsigned long long* brow[2];
    #pragma unroll
    for (int fm = 0; fm < 2; ++fm) {
        int row = m0 + wave * 32 + fm * 16 + ml;
        float4 rc = rowco[row];
        pA[fm] = rc.x; pG[fm] = rc.y; th[fm] = rc.z;
        brow[fm] = bits + (size_t)row * WPR;
    }

    float4v acc[2][8];
    #pragma unroll
    for (int i = 0; i < 2; ++i)
        #pragma unroll
        for (int j = 0; j < 8; ++j) acc[i][j] = (float4v){0.f, 0.f, 0.f, 0.f};

    // prologue: stage step 0
    {
        ushort8v b0 = *(const ushort8v*)&bsrc[k0];
        ushort8v b1 = *(const ushort8v*)&bsrc[k0 + 8];
        *(ushort8v*)&Bs[0][srow * 40 + skh]     = b0;
        *(ushort8v*)&Bs[0][srow * 40 + skh + 8] = b1;
    }
    __syncthreads();

    const int nsteps = kchunk >> 5;
    for (int i = 0; i < nsteps; ++i) {
        const int kk = k0 + i * 32;
        const int p = i & 1;
        // prefetch next-step B into registers (consumed by ds_write at bottom)
        ushort8v nb0, nb1;
        if (i + 1 < nsteps) {
            nb0 = *(const ushort8v*)&bsrc[kk + 32];
            nb1 = *(const ushort8v*)&bsrc[kk + 40];
        }
        // ---- A-gen (registers only; tab/bits are L1-hot) ----
        const int word = kk >> 6;
        const int kb = (kk & 63) + g * 8;
        unsigned long long wv0 = brow[0][word];
        unsigned long long wv1 = brow[1][word];
        const float4v* q = (const float4v*)&tab2f[2 * (kk + g * 8)];
        float4v q0 = q[0], q1 = q[1], q2 = q[2], q3 = q[3];
        short8 afr[2];
        #pragma unroll
        for (int fm = 0; fm < 2; ++fm) {
            unsigned int wh = (unsigned int)((fm ? wv1 : wv0) >> kb);
            ushort8v af;
            #pragma unroll
            for (int jj = 0; jj < 4; ++jj) {
                float4v v = (jj == 0) ? q0 : (jj == 1) ? q1 : (jj == 2) ? q2 : q3;
                float x0 = ((wh >> (2 * jj)) & 1u)     ? (v[0] > th[fm] ? pA[fm] * v[0] : pG[fm] * v[1]) : 0.f;
                float x1 = ((wh >> (2 * jj + 1)) & 1u) ? (v[2] > th[fm] ? pA[fm] * v[2] : pG[fm] * v[3]) : 0.f;
                union { __hip_bfloat162 b2; unsigned int u; } cv;
                cv.b2 = __float22bfloat162_rn(make_float2(x0, x1));
                ((unsigned int*)&af)[jj] = cv.u;
            }
            afr[fm] = as_s8(af);
        }
        // ---- B fragments from LDS + MFMA ----
        #pragma unroll
        for (int fn = 0; fn < 8; ++fn) {
            short8 b = as_s8(*(const ushort8v*)&Bs[p][(fn * 16 + ml) * 40 + g * 8]);
            acc[0][fn] = __builtin_amdgcn_mfma_f32_16x16x32_bf16(afr[0], b, acc[0][fn], 0, 0, 0);
            acc[1][fn] = __builtin_amdgcn_mfma_f32_16x16x32_bf16(afr[1], b, acc[1][fn], 0, 0, 0);
        }
        // ---- stage next step, single barrier ----
        if (i + 1 < nsteps) {
            *(ushort8v*)&Bs[1 - p][srow * 40 + skh]     = nb0;
            *(ushort8v*)&Bs[1 - p][srow * 40 + skh + 8] = nb1;
            __syncthreads();
        }
    }

    // epilogue: fp16 partials
    unsigned short* pbase = parth + ((size_t)ks << 20);
    #pragma unroll
    for (int fm = 0; fm < 2; ++fm)
        #pragma unroll
        for (int fn = 0; fn < 8; ++fn)
            #pragma unroll
            for (int r = 0; r < 4; ++r) {
                __half h = __float2half(acc[fm][fn][r]);
                pbase[(size_t)(m0 + wave * 32 + fm * 16 + g * 4 + r) * 256 + n0 + fn * 16 + ml] =
                    *(unsigned short*)&h;
            }
}

// ---------------- reduce fp16 split-K partials + ELU (P already normalized) ----------------
__global__ __launch_bounds__(256) void att_reduce(const unsigned short* __restrict__ parth,
                                                  float* __restrict__ outf,
                                                  unsigned short* __restrict__ hrow, int nsplit) {
    const int idx = (blockIdx.x * 256 + threadIdx.x) * 8;
    float s[8] = {0.f, 0.f, 0.f, 0.f, 0.f, 0.f, 0.f, 0.f};
    for (int sp = 0; sp < nsplit; ++sp) {
        ushort8v v = *(const ushort8v*)&parth[((size_t)sp << 20) + idx];
        #pragma unroll
        for (int j = 0; j < 8; ++j) {
            unsigned short u = v[j];
            s[j] += __half2float(*(__half*)&u);
        }
    }
    ushort8v hb;
    float4v o0, o1;
    #pragma unroll
    for (int j = 0; j < 8; ++j) {
        float x = s[j];
        x = x > 0.f ? x : (__expf(x) - 1.f);
        hb[j] = f2bf(x);
        if (j < 4) o0[j] = x; else o1[j - 4] = x;
    }
    if (outf) {
        *(float4v*)&outf[idx] = o0;
        *(float4v*)&outf[idx + 4] = o1;
    }
    *(ushort8v*)&hrow[idx] = hb;
}

extern "C" void kernel_launch(void* const* d_in, const int* in_sizes, int n_in,
                              void* d_out, int out_size, void* d_ws, size_t ws_size,
                              hipStream_t stream) {
    const float* input = (const float*)d_in[0];
    const int*   adj   = (const int*)d_in[1];
    const float* W0    = (const float*)d_in[2];
    const float* W1    = (const float*)d_in[3];
    const float* a1    = (const float*)d_in[4];
    const float* W2    = (const float*)d_in[5];
    const float* a2    = (const float*)d_in[6];
    const float* W3    = (const float*)d_in[7];
    const float* a3    = (const float*)d_in[8];
    float* out = (float*)d_out;
    char* ws = (char*)d_ws;

    unsigned long long* bits = (unsigned long long*)(ws);                 // 2 MB
    unsigned short* h0   = (unsigned short*)(ws + (2u << 20));            // 2 MB
    unsigned short* h1   = (unsigned short*)(ws + (4u << 20));            // 2 MB
    unsigned short* Whbt = (unsigned short*)(ws + (6u << 20));            // 2 MB
    unsigned short* Wbt  = (unsigned short*)(ws + (8u << 20));            // 512 KB
    float*  f1f2  = (float*)(ws + (9u << 20));                            // 3 layers x 32 KB
    float4* rowco = (float4*)(ws + (10u << 20));                          // 64 KB
    float2* tab2  = (float2*)(ws + (10u << 20) + (256u << 10));           // 32 KB
    unsigned short* parth = (unsigned short*)(ws + (13u << 20));          // 2 MB * SPLIT (fp16)

    const size_t base = 13u << 20;
    int SPLIT = 16;
    while (SPLIT > 1 && base + (size_t)SPLIT * (2u << 20) > ws_size) SPLIT >>= 1;
    const int kchunk = NN / SPLIT;

    float* f1f2_l[3] = { f1f2, f1f2 + 8192, f1f2 + 16384 };

    setup<<<5124, 256, 0, stream>>>(adj, input, W0, W1, W2, W3, bits, h0, Wbt, f1f2);

    // h = input @ W0 -> h1
    proj_gemm<<<256, 256, 0, stream>>>(h0, Wbt + 0 * 65536, nullptr, nullptr, nullptr, h1);

    // layer 1
    proj_gemm<<<256, 256, 0, stream>>>(h1, Wbt + 1 * 65536, a1, f1f2_l[0], Whbt, nullptr);
    rowcoef<<<512, 256, 0, stream>>>(bits, f1f2_l[0], rowco, tab2);
    att_gemm<<<64 * SPLIT, 256, 0, stream>>>(bits, rowco, (const float*)tab2, Whbt, parth, kchunk);
    att_reduce<<<512, 256, 0, stream>>>(parth, nullptr, h0, SPLIT);

    // layer 2
    proj_gemm<<<256, 256, 0, stream>>>(h0, Wbt + 2 * 65536, a2, f1f2_l[1], Whbt, nullptr);
    rowcoef<<<512, 256, 0, stream>>>(bits, f1f2_l[1], rowco, tab2);
    att_gemm<<<64 * SPLIT, 256, 0, stream>>>(bits, rowco, (const float*)tab2, Whbt, parth, kchunk);
    att_reduce<<<512, 256, 0, stream>>>(parth, nullptr, h1, SPLIT);

    // layer 3
    proj_gemm<<<256, 256, 0, stream>>>(h1, Wbt + 3 * 65536, a3, f1f2_l[2], Whbt, nullptr);
    rowcoef<<<512, 256, 0, stream>>>(bits, f1f2_l[2], rowco, tab2);
    att_gemm<<<64 * SPLIT, 256, 0, stream>>>(bits, rowco, (const float*)tab2, Whbt, parth, kchunk);
    att_reduce<<<512, 256, 0, stream>>>(parth, out, h0, SPLIT);
}

// Round 9
// 282.070 us; speedup vs baseline: 1.3716x; 1.0282x over previous
//
#include <hip/hip_runtime.h>
#include <hip/hip_bf16.h>
#include <hip/hip_fp16.h>
#include <cstdint>
#include <cstddef>

#define NN 4096
#define FD 256
#define WPR 64  // 64-bit words per adjacency row

typedef __attribute__((ext_vector_type(8))) unsigned short ushort8v;
typedef __attribute__((ext_vector_type(4))) unsigned short ushort4v;
typedef __attribute__((ext_vector_type(8))) short short8;
typedef __attribute__((ext_vector_type(4))) float float4v;

#define C1 30.0f
#define C2 0.3f    // 0.01 * C1

static __device__ __forceinline__ unsigned short f2bf(float x) {
    union { float f; unsigned int u; } v; v.f = x;
    unsigned int r = v.u + 0x7FFFu + ((v.u >> 16) & 1u);
    return (unsigned short)(r >> 16);
}

static __device__ __forceinline__ short8 as_s8(ushort8v v) {
    union { ushort8v u; short8 s; } x; x.u = v; return x.s;
}

// ---------------- fused setup: pack adj + cvt input + cvt weights + zero f1f2 ----------------
__global__ __launch_bounds__(256) void setup(const int* __restrict__ adj,
                                             const float* __restrict__ input,
                                             const float* __restrict__ W0, const float* __restrict__ W1,
                                             const float* __restrict__ W2, const float* __restrict__ W3,
                                             unsigned long long* __restrict__ bits,
                                             unsigned short* __restrict__ hb,
                                             unsigned short* __restrict__ Wbt,
                                             float* __restrict__ f1f2) {
    const int b = blockIdx.x;
    const int t = threadIdx.x;
    if (b < 4096) {
        const int wave = t >> 6, lane = t & 63;
        const int* arow = adj + (size_t)b * NN;
        #pragma unroll
        for (int it = 0; it < NN / 256; ++it) {
            int j = it * 256 + wave * 64 + lane;
            unsigned long long m = __ballot(arow[j] > 0);
            if (lane == 0) bits[(size_t)b * WPR + (it * 4 + wave)] = m;
        }
        hb[(size_t)b * 256 + t] = f2bf(input[(size_t)b * 256 + t]);
    } else if (b < 5120) {
        int idx = (b - 4096) * 256 + t;
        int mat = idx >> 16;
        int within = idx & 65535;
        int n = within >> 8, k = within & 255;
        const float* W = (mat == 0) ? W0 : (mat == 1) ? W1 : (mat == 2) ? W2 : W3;
        Wbt[idx] = f2bf(W[k * 256 + n]);
    } else {
        #pragma unroll
        for (int i = 0; i < 24; ++i) {
            int pos = i * 1024 + (b - 5120) * 256 + t;
            f1f2[pos] = 0.f;
        }
    }
}

// ---------------- projection GEMM v2: 32x64 tiles, grid 512 (2 blocks/CU) ----------------
__global__ __launch_bounds__(256) void proj_gemm(const unsigned short* __restrict__ A,
                                                 const unsigned short* __restrict__ Bt,
                                                 const float* __restrict__ av,
                                                 float* __restrict__ f1f2,
                                                 unsigned short* __restrict__ Cbt,
                                                 unsigned short* __restrict__ Crow) {
    const int t = threadIdx.x;
    const int bm = blockIdx.x >> 2, bn = blockIdx.x & 3;
    const int m0 = bm * 32, n0 = bn * 64;
    __shared__ unsigned short As[32 * 264];
    __shared__ unsigned short Bs[64 * 264];
    const int lane = t & 63, wave = t >> 6;
    const int wm = (wave >> 1) * 16, wn = (wave & 1) * 32;
    const int g = lane >> 4, ml = lane & 15;
    {
        int ar = t >> 3, ac0 = (t & 7) * 8;
        #pragma unroll
        for (int i = 0; i < 4; ++i) {
            int col = ac0 + i * 64;
            *(ushort8v*)&As[ar * 264 + col] = *(const ushort8v*)&A[(size_t)(m0 + ar) * 256 + col];
        }
        int br = t >> 2, bc0 = (t & 3) * 8;
        #pragma unroll
        for (int i = 0; i < 8; ++i) {
            int col = bc0 + i * 32;
            *(ushort8v*)&Bs[br * 264 + col] = *(const ushort8v*)&Bt[(size_t)(n0 + br) * 256 + col];
        }
    }
    __syncthreads();
    float4v acc[2] = {{0.f,0.f,0.f,0.f},{0.f,0.f,0.f,0.f}};
    #pragma unroll
    for (int kk = 0; kk < 256; kk += 32) {
        const int kc = kk + g * 8;
        short8 a = as_s8(*(const ushort8v*)&As[(wm + ml) * 264 + kc]);
        #pragma unroll
        for (int fn = 0; fn < 2; ++fn) {
            short8 b = as_s8(*(const ushort8v*)&Bs[(wn + fn * 16 + ml) * 264 + kc]);
            acc[fn] = __builtin_amdgcn_mfma_f32_16x16x32_bf16(a, b, acc[fn], 0, 0, 0);
        }
    }

    const int rb = wm + g * 4;   // local m base (+r)
    if (Crow) {
        #pragma unroll
        for (int fn = 0; fn < 2; ++fn)
            #pragma unroll
            for (int r = 0; r < 4; ++r)
                Crow[(size_t)(m0 + rb + r) * 256 + n0 + wn + fn * 16 + ml] = f2bf(acc[fn][r]);
    }

    if (f1f2) {
        float a1c[2], a2c[2];
        #pragma unroll
        for (int fn = 0; fn < 2; ++fn) {
            a1c[fn] = av[n0 + wn + fn * 16 + ml];
            a2c[fn] = av[256 + n0 + wn + fn * 16 + ml];
        }
        #pragma unroll
        for (int r = 0; r < 4; ++r) {
            float s1 = acc[0][r] * a1c[0] + acc[1][r] * a1c[1];
            float s2 = acc[0][r] * a2c[0] + acc[1][r] * a2c[1];
            #pragma unroll
            for (int off = 1; off < 16; off <<= 1) {
                s1 += __shfl_xor(s1, off, 64);
                s2 += __shfl_xor(s2, off, 64);
            }
            if (ml == 0) {
                int row = m0 + rb + r;
                atomicAdd(&f1f2[row], s1);
                atomicAdd(&f1f2[4096 + row], s2);
            }
        }
    }

    if (Cbt) {
        unsigned short* T = As;          // 64 x 40 = 2560 shorts, fits
        __syncthreads();
        #pragma unroll
        for (int fn = 0; fn < 2; ++fn)
            #pragma unroll
            for (int r = 0; r < 4; ++r)
                T[(wn + fn * 16 + ml) * 40 + rb + r] = f2bf(acc[fn][r]);
        __syncthreads();
        const int tr = t >> 2, tc = (t & 3) * 8;
        *(ushort8v*)&Cbt[(size_t)(n0 + tr) * 4096 + m0 + tc] = *(const ushort8v*)&T[tr * 40 + tc];
    }
}

// ---------------- per-row coefficients + global exp tables ----------------
__global__ __launch_bounds__(256) void rowcoef(const unsigned long long* __restrict__ bits,
                                               const float* __restrict__ f1f2,
                                               float4* __restrict__ rowco,
                                               float2* __restrict__ tab2g) {
    __shared__ float2 tl[4096];
    const int t = threadIdx.x;
    const float* f2p = f1f2 + 4096;
    #pragma unroll
    for (int i = 0; i < 16; ++i) {
        float v = f2p[i * 256 + t];
        float2 pr = make_float2(__expf(v - C1), __expf(0.01f * v - C2));
        tl[i * 256 + t] = pr;
        if (blockIdx.x == 0) tab2g[i * 256 + t] = pr;
    }
    __syncthreads();
    const int lane = t & 63, wave = t >> 6;
    for (int rr = 0; rr < 2; ++rr) {
        const int row = blockIdx.x * 8 + wave * 2 + rr;
        const unsigned long long wl = bits[(size_t)row * WPR + lane];
        const float f1r = f1f2[row];
        const float th = __expf(-f1r - C1);
        float mx = 0.f, S1 = 0.f, S2 = 0.f;
        #pragma unroll 16
        for (int b = 0; b < 64; ++b) {
            unsigned long long w = __shfl(wl, b, 64);
            bool bit = (w >> lane) & 1ULL;
            float2 v = tl[b * 64 + lane];
            float ebm = bit ? v.x : 0.f;
            mx = fmaxf(mx, ebm);
            bool cond = v.x > th;
            S1 += (bit && cond)  ? v.x : 0.f;
            S2 += (bit && !cond) ? v.y : 0.f;
        }
        #pragma unroll
        for (int off = 1; off < 64; off <<= 1) {
            mx = fmaxf(mx, __shfl_xor(mx, off, 64));
            S1 += __shfl_xor(S1, off, 64);
            S2 += __shfl_xor(S2, off, 64);
        }
        if (lane == 0) {
            float M  = C1 + __logf(mx);
            float fm_ = f1r + M;
            float m  = fm_ > 0.f ? fm_ : 0.01f * fm_;    // lrelu
            float alpha = __expf(fminf(f1r + C1 - m, 60.f));
            float gamma = __expf(fminf(0.01f * (f1r + C1) - m, 60.f));
            float inv = 1.0f / (alpha * S1 + gamma * S2);
            rowco[row] = make_float4(alpha * inv, gamma * inv, th, 0.f);
        }
    }
}

// ---------------- attention GEMM v9: as v8 but permuted coalesced fp16 epilogue ----------------
__global__ __launch_bounds__(256, 4) void att_gemm(const unsigned long long* __restrict__ bits,
                                                   const float4* __restrict__ rowco,
                                                   const float* __restrict__ tab2f,
                                                   const unsigned short* __restrict__ Bt,  // Whbt [256][4096]
                                                   unsigned short* __restrict__ parth, int kchunk) {
    const int t = threadIdx.x;
    const int bm = blockIdx.x & 31;
    const int bn = (blockIdx.x >> 5) & 1;
    const int ks = blockIdx.x >> 6;
    const int m0 = bm * 128, n0 = bn * 128;
    const int k0 = ks * kchunk;
    __shared__ unsigned short Bs[2][128 * 40];
    const int lane = t & 63, wave = t >> 6;
    const int g = lane >> 4, ml = lane & 15;

    const int srow = t >> 1, skh = (t & 1) * 16;
    const unsigned short* bsrc = Bt + (size_t)(n0 + srow) * 4096 + skh;

    float pA[2], pG[2], th[2];
    const unsigned long long* brow[2];
    #pragma unroll
    for (int fm = 0; fm < 2; ++fm) {
        int row = m0 + wave * 32 + fm * 16 + ml;
        float4 rc = rowco[row];
        pA[fm] = rc.x; pG[fm] = rc.y; th[fm] = rc.z;
        brow[fm] = bits + (size_t)row * WPR;
    }

    float4v acc[2][8];
    #pragma unroll
    for (int i = 0; i < 2; ++i)
        #pragma unroll
        for (int j = 0; j < 8; ++j) acc[i][j] = (float4v){0.f, 0.f, 0.f, 0.f};

    {
        ushort8v b0 = *(const ushort8v*)&bsrc[k0];
        ushort8v b1 = *(const ushort8v*)&bsrc[k0 + 8];
        *(ushort8v*)&Bs[0][srow * 40 + skh]     = b0;
        *(ushort8v*)&Bs[0][srow * 40 + skh + 8] = b1;
    }
    __syncthreads();

    const int nsteps = kchunk >> 5;
    for (int i = 0; i < nsteps; ++i) {
        const int kk = k0 + i * 32;
        const int p = i & 1;
        ushort8v nb0, nb1;
        if (i + 1 < nsteps) {
            nb0 = *(const ushort8v*)&bsrc[kk + 32];
            nb1 = *(const ushort8v*)&bsrc[kk + 40];
        }
        const int word = kk >> 6;
        const int kb = (kk & 63) + g * 8;
        unsigned long long wv0 = brow[0][word];
        unsigned long long wv1 = brow[1][word];
        const float4v* q = (const float4v*)&tab2f[2 * (kk + g * 8)];
        float4v q0 = q[0], q1 = q[1], q2 = q[2], q3 = q[3];
        short8 afr[2];
        #pragma unroll
        for (int fm = 0; fm < 2; ++fm) {
            unsigned int wh = (unsigned int)((fm ? wv1 : wv0) >> kb);
            ushort8v af;
            #pragma unroll
            for (int jj = 0; jj < 4; ++jj) {
                float4v v = (jj == 0) ? q0 : (jj == 1) ? q1 : (jj == 2) ? q2 : q3;
                float x0 = ((wh >> (2 * jj)) & 1u)     ? (v[0] > th[fm] ? pA[fm] * v[0] : pG[fm] * v[1]) : 0.f;
                float x1 = ((wh >> (2 * jj + 1)) & 1u) ? (v[2] > th[fm] ? pA[fm] * v[2] : pG[fm] * v[3]) : 0.f;
                union { __hip_bfloat162 b2; unsigned int u; } cv;
                cv.b2 = __float22bfloat162_rn(make_float2(x0, x1));
                ((unsigned int*)&af)[jj] = cv.u;
            }
            afr[fm] = as_s8(af);
        }
        #pragma unroll
        for (int fn = 0; fn < 8; ++fn) {
            short8 b = as_s8(*(const ushort8v*)&Bs[p][(fn * 16 + ml) * 40 + g * 8]);
            acc[0][fn] = __builtin_amdgcn_mfma_f32_16x16x32_bf16(afr[0], b, acc[0][fn], 0, 0, 0);
            acc[1][fn] = __builtin_amdgcn_mfma_f32_16x16x32_bf16(afr[1], b, acc[1][fn], 0, 0, 0);
        }
        if (i + 1 < nsteps) {
            *(ushort8v*)&Bs[1 - p][srow * 40 + skh]     = nb0;
            *(ushort8v*)&Bs[1 - p][srow * 40 + skh + 8] = nb1;
            __syncthreads();
        }
    }

    // permuted coalesced fp16 epilogue: P = ((wave*16+fm*8+fn)*64 + lane)*4 + r
    unsigned short* pbase = parth + ((size_t)ks << 20) + (size_t)(bm * 2 + bn) * 16384;
    #pragma unroll
    for (int fm = 0; fm < 2; ++fm)
        #pragma unroll
        for (int fn = 0; fn < 8; ++fn) {
            ushort4v v4;
            #pragma unroll
            for (int r = 0; r < 4; ++r) {
                __half h = __float2half(acc[fm][fn][r]);
                v4[r] = *(unsigned short*)&h;
            }
            *(ushort4v*)&pbase[((wave * 16 + fm * 8 + fn) * 64 + lane) * 4] = v4;
        }
}

// ---------------- reduce permuted fp16 split-K partials + ELU, coalesced ----------------
template<int NS>
__global__ __launch_bounds__(256) void att_reduce(const unsigned short* __restrict__ parth,
                                                  float* __restrict__ outf,
                                                  unsigned short* __restrict__ hrow) {
    const int flat = (blockIdx.x * 256 + threadIdx.x) * 8;   // grid 512 covers 1M elems
    float s[8] = {0.f, 0.f, 0.f, 0.f, 0.f, 0.f, 0.f, 0.f};
    #pragma unroll
    for (int sp = 0; sp < NS; ++sp) {
        ushort8v v = *(const ushort8v*)&parth[((size_t)sp << 20) + flat];
        #pragma unroll
        for (int j = 0; j < 8; ++j) {
            unsigned short u = v[j];
            s[j] += __half2float(*(__half*)&u);
        }
    }
    // decode permuted index
    const int tile  = flat >> 14;
    const int inner = flat & 16383;
    const int widx = inner >> 8;          // wave*16 + fm*8 + fn
    const int ls   = (inner >> 2) & 63;   // g*16 + ml (even)
    const int bm = tile >> 1, bn = tile & 1;
    const int wavea = widx >> 4, fm = (widx >> 3) & 1, fn = widx & 7;
    const int g = ls >> 4, ml = ls & 15;
    const int row0 = bm * 128 + wavea * 32 + fm * 16 + g * 4;
    const int col  = bn * 128 + fn * 16 + ml;
    #pragma unroll
    for (int r = 0; r < 4; ++r) {
        float x0 = s[r];
        float x1 = s[4 + r];
        x0 = x0 > 0.f ? x0 : (__expf(x0) - 1.f);
        x1 = x1 > 0.f ? x1 : (__expf(x1) - 1.f);
        unsigned int hp = (unsigned int)f2bf(x0) | ((unsigned int)f2bf(x1) << 16);
        *(unsigned int*)&hrow[(size_t)(row0 + r) * 256 + col] = hp;
        if (outf) *(float2*)&outf[(size_t)(row0 + r) * 256 + col] = make_float2(x0, x1);
    }
}

static void launch_reduce(int SPLIT, const unsigned short* parth, float* outf,
                          unsigned short* hrow, hipStream_t stream) {
    switch (SPLIT) {
        case 16: att_reduce<16><<<512, 256, 0, stream>>>(parth, outf, hrow); break;
        case 8:  att_reduce<8><<<512, 256, 0, stream>>>(parth, outf, hrow); break;
        case 4:  att_reduce<4><<<512, 256, 0, stream>>>(parth, outf, hrow); break;
        case 2:  att_reduce<2><<<512, 256, 0, stream>>>(parth, outf, hrow); break;
        default: att_reduce<1><<<512, 256, 0, stream>>>(parth, outf, hrow); break;
    }
}

extern "C" void kernel_launch(void* const* d_in, const int* in_sizes, int n_in,
                              void* d_out, int out_size, void* d_ws, size_t ws_size,
                              hipStream_t stream) {
    const float* input = (const float*)d_in[0];
    const int*   adj   = (const int*)d_in[1];
    const float* W0    = (const float*)d_in[2];
    const float* W1    = (const float*)d_in[3];
    const float* a1    = (const float*)d_in[4];
    const float* W2    = (const float*)d_in[5];
    const float* a2    = (const float*)d_in[6];
    const float* W3    = (const float*)d_in[7];
    const float* a3    = (const float*)d_in[8];
    float* out = (float*)d_out;
    char* ws = (char*)d_ws;

    unsigned long long* bits = (unsigned long long*)(ws);                 // 2 MB
    unsigned short* h0   = (unsigned short*)(ws + (2u << 20));            // 2 MB
    unsigned short* h1   = (unsigned short*)(ws + (4u << 20));            // 2 MB
    unsigned short* Whbt = (unsigned short*)(ws + (6u << 20));            // 2 MB
    unsigned short* Wbt  = (unsigned short*)(ws + (8u << 20));            // 512 KB
    float*  f1f2  = (float*)(ws + (9u << 20));                            // 3 layers x 32 KB
    float4* rowco = (float4*)(ws + (10u << 20));                          // 64 KB
    float2* tab2  = (float2*)(ws + (10u << 20) + (256u << 10));           // 32 KB
    unsigned short* parth = (unsigned short*)(ws + (13u << 20));          // 2 MB * SPLIT (fp16)

    const size_t base = 13u << 20;
    int SPLIT = 16;
    while (SPLIT > 1 && base + (size_t)SPLIT * (2u << 20) > ws_size) SPLIT >>= 1;
    const int kchunk = NN / SPLIT;

    float* f1f2_l[3] = { f1f2, f1f2 + 8192, f1f2 + 16384 };

    setup<<<5124, 256, 0, stream>>>(adj, input, W0, W1, W2, W3, bits, h0, Wbt, f1f2);

    // h = input @ W0 -> h1
    proj_gemm<<<512, 256, 0, stream>>>(h0, Wbt + 0 * 65536, nullptr, nullptr, nullptr, h1);

    // layer 1
    proj_gemm<<<512, 256, 0, stream>>>(h1, Wbt + 1 * 65536, a1, f1f2_l[0], Whbt, nullptr);
    rowcoef<<<512, 256, 0, stream>>>(bits, f1f2_l[0], rowco, tab2);
    att_gemm<<<64 * SPLIT, 256, 0, stream>>>(bits, rowco, (const float*)tab2, Whbt, parth, kchunk);
    launch_reduce(SPLIT, parth, nullptr, h0, stream);

    // layer 2
    proj_gemm<<<512, 256, 0, stream>>>(h0, Wbt + 2 * 65536, a2, f1f2_l[1], Whbt, nullptr);
    rowcoef<<<512, 256, 0, stream>>>(bits, f1f2_l[1], rowco, tab2);
    att_gemm<<<64 * SPLIT, 256, 0, stream>>>(bits, rowco, (const float*)tab2, Whbt, parth, kchunk);
    launch_reduce(SPLIT, parth, nullptr, h1, stream);

    // layer 3
    proj_gemm<<<512, 256, 0, stream>>>(h1, Wbt + 3 * 65536, a3, f1f2_l[2], Whbt, nullptr);
    rowcoef<<<512, 256, 0, stream>>>(bits, f1f2_l[2], rowco, tab2);
    att_gemm<<<64 * SPLIT, 256, 0, stream>>>(bits, rowco, (const float*)tab2, Whbt, parth, kchunk);
    launch_reduce(SPLIT, parth, out, h0, stream);
}

// Round 10
// 277.047 us; speedup vs baseline: 1.3964x; 1.0181x over previous
//
#include <hip/hip_runtime.h>
#include <hip/hip_bf16.h>
#include <hip/hip_fp16.h>
#include <cstdint>
#include <cstddef>

#define NN 4096
#define FD 256
#define WPR 64  // 64-bit words per adjacency row

typedef __attribute__((ext_vector_type(8))) unsigned short ushort8v;
typedef __attribute__((ext_vector_type(4))) unsigned short ushort4v;
typedef __attribute__((ext_vector_type(8))) short short8;
typedef __attribute__((ext_vector_type(4))) float float4v;

#define C1 30.0f
#define C2 0.3f    // 0.01 * C1

static __device__ __forceinline__ unsigned short f2bf(float x) {
    union { float f; unsigned int u; } v; v.f = x;
    unsigned int r = v.u + 0x7FFFu + ((v.u >> 16) & 1u);
    return (unsigned short)(r >> 16);
}

static __device__ __forceinline__ short8 as_s8(ushort8v v) {
    union { ushort8v u; short8 s; } x; x.u = v; return x.s;
}

// ---------------- fused setup: pack adj + cvt input + cvt weights + zero f1f2 ----------------
__global__ __launch_bounds__(256) void setup(const int* __restrict__ adj,
                                             const float* __restrict__ input,
                                             const float* __restrict__ W0, const float* __restrict__ W1,
                                             const float* __restrict__ W2, const float* __restrict__ W3,
                                             unsigned long long* __restrict__ bits,
                                             unsigned short* __restrict__ hb,
                                             unsigned short* __restrict__ Wbt,
                                             float* __restrict__ f1f2) {
    const int b = blockIdx.x;
    const int t = threadIdx.x;
    if (b < 4096) {
        const int wave = t >> 6, lane = t & 63;
        const int* arow = adj + (size_t)b * NN;
        #pragma unroll
        for (int it = 0; it < NN / 256; ++it) {
            int j = it * 256 + wave * 64 + lane;
            unsigned long long m = __ballot(arow[j] > 0);
            if (lane == 0) bits[(size_t)b * WPR + (it * 4 + wave)] = m;
        }
        hb[(size_t)b * 256 + t] = f2bf(input[(size_t)b * 256 + t]);
    } else if (b < 5120) {
        int idx = (b - 4096) * 256 + t;
        int mat = idx >> 16;
        int within = idx & 65535;
        int n = within >> 8, k = within & 255;
        const float* W = (mat == 0) ? W0 : (mat == 1) ? W1 : (mat == 2) ? W2 : W3;
        Wbt[idx] = f2bf(W[k * 256 + n]);
    } else {
        #pragma unroll
        for (int i = 0; i < 24; ++i) {
            int pos = i * 1024 + (b - 5120) * 256 + t;
            f1f2[pos] = 0.f;
        }
    }
}

// ---------------- projection GEMM: 32x64 tiles, grid 512 (2 blocks/CU) ----------------
__global__ __launch_bounds__(256) void proj_gemm(const unsigned short* __restrict__ A,
                                                 const unsigned short* __restrict__ Bt,
                                                 const float* __restrict__ av,
                                                 float* __restrict__ f1f2,
                                                 unsigned short* __restrict__ Cbt,
                                                 unsigned short* __restrict__ Crow) {
    const int t = threadIdx.x;
    const int bm = blockIdx.x >> 2, bn = blockIdx.x & 3;
    const int m0 = bm * 32, n0 = bn * 64;
    __shared__ unsigned short As[32 * 264];
    __shared__ unsigned short Bs[64 * 264];
    const int lane = t & 63, wave = t >> 6;
    const int wm = (wave >> 1) * 16, wn = (wave & 1) * 32;
    const int g = lane >> 4, ml = lane & 15;
    {
        int ar = t >> 3, ac0 = (t & 7) * 8;
        #pragma unroll
        for (int i = 0; i < 4; ++i) {
            int col = ac0 + i * 64;
            *(ushort8v*)&As[ar * 264 + col] = *(const ushort8v*)&A[(size_t)(m0 + ar) * 256 + col];
        }
        int br = t >> 2, bc0 = (t & 3) * 8;
        #pragma unroll
        for (int i = 0; i < 8; ++i) {
            int col = bc0 + i * 32;
            *(ushort8v*)&Bs[br * 264 + col] = *(const ushort8v*)&Bt[(size_t)(n0 + br) * 256 + col];
        }
    }
    __syncthreads();
    float4v acc[2] = {{0.f,0.f,0.f,0.f},{0.f,0.f,0.f,0.f}};
    #pragma unroll
    for (int kk = 0; kk < 256; kk += 32) {
        const int kc = kk + g * 8;
        short8 a = as_s8(*(const ushort8v*)&As[(wm + ml) * 264 + kc]);
        #pragma unroll
        for (int fn = 0; fn < 2; ++fn) {
            short8 b = as_s8(*(const ushort8v*)&Bs[(wn + fn * 16 + ml) * 264 + kc]);
            acc[fn] = __builtin_amdgcn_mfma_f32_16x16x32_bf16(a, b, acc[fn], 0, 0, 0);
        }
    }

    const int rb = wm + g * 4;
    if (Crow) {
        #pragma unroll
        for (int fn = 0; fn < 2; ++fn)
            #pragma unroll
            for (int r = 0; r < 4; ++r)
                Crow[(size_t)(m0 + rb + r) * 256 + n0 + wn + fn * 16 + ml] = f2bf(acc[fn][r]);
    }

    if (f1f2) {
        float a1c[2], a2c[2];
        #pragma unroll
        for (int fn = 0; fn < 2; ++fn) {
            a1c[fn] = av[n0 + wn + fn * 16 + ml];
            a2c[fn] = av[256 + n0 + wn + fn * 16 + ml];
        }
        #pragma unroll
        for (int r = 0; r < 4; ++r) {
            float s1 = acc[0][r] * a1c[0] + acc[1][r] * a1c[1];
            float s2 = acc[0][r] * a2c[0] + acc[1][r] * a2c[1];
            #pragma unroll
            for (int off = 1; off < 16; off <<= 1) {
                s1 += __shfl_xor(s1, off, 64);
                s2 += __shfl_xor(s2, off, 64);
            }
            if (ml == 0) {
                int row = m0 + rb + r;
                atomicAdd(&f1f2[row], s1);
                atomicAdd(&f1f2[4096 + row], s2);
            }
        }
    }

    if (Cbt) {
        unsigned short* T = As;
        __syncthreads();
        #pragma unroll
        for (int fn = 0; fn < 2; ++fn)
            #pragma unroll
            for (int r = 0; r < 4; ++r)
                T[(wn + fn * 16 + ml) * 40 + rb + r] = f2bf(acc[fn][r]);
        __syncthreads();
        const int tr = t >> 2, tc = (t & 3) * 8;
        *(ushort8v*)&Cbt[(size_t)(n0 + tr) * 4096 + m0 + tc] = *(const ushort8v*)&T[tr * 40 + tc];
    }
}

// ---------------- per-row coefficients + global exp tables ----------------
__global__ __launch_bounds__(256) void rowcoef(const unsigned long long* __restrict__ bits,
                                               const float* __restrict__ f1f2,
                                               float4* __restrict__ rowco,
                                               float2* __restrict__ tab2g) {
    __shared__ float2 tl[4096];
    const int t = threadIdx.x;
    const float* f2p = f1f2 + 4096;
    #pragma unroll
    for (int i = 0; i < 16; ++i) {
        float v = f2p[i * 256 + t];
        float2 pr = make_float2(__expf(v - C1), __expf(0.01f * v - C2));
        tl[i * 256 + t] = pr;
        if (blockIdx.x == 0) tab2g[i * 256 + t] = pr;
    }
    __syncthreads();
    const int lane = t & 63, wave = t >> 6;
    for (int rr = 0; rr < 2; ++rr) {
        const int row = blockIdx.x * 8 + wave * 2 + rr;
        const unsigned long long wl = bits[(size_t)row * WPR + lane];
        const float f1r = f1f2[row];
        const float th = __expf(-f1r - C1);
        float mx = 0.f, S1 = 0.f, S2 = 0.f;
        #pragma unroll 16
        for (int b = 0; b < 64; ++b) {
            unsigned long long w = __shfl(wl, b, 64);
            bool bit = (w >> lane) & 1ULL;
            float2 v = tl[b * 64 + lane];
            float ebm = bit ? v.x : 0.f;
            mx = fmaxf(mx, ebm);
            bool cond = v.x > th;
            S1 += (bit && cond)  ? v.x : 0.f;
            S2 += (bit && !cond) ? v.y : 0.f;
        }
        #pragma unroll
        for (int off = 1; off < 64; off <<= 1) {
            mx = fmaxf(mx, __shfl_xor(mx, off, 64));
            S1 += __shfl_xor(S1, off, 64);
            S2 += __shfl_xor(S2, off, 64);
        }
        if (lane == 0) {
            float M  = C1 + __logf(mx);
            float fm_ = f1r + M;
            float m  = fm_ > 0.f ? fm_ : 0.01f * fm_;    // lrelu
            float alpha = __expf(fminf(f1r + C1 - m, 60.f));
            float gamma = __expf(fminf(0.01f * (f1r + C1) - m, 60.f));
            float inv = 1.0f / (alpha * S1 + gamma * S2);
            rowco[row] = make_float4(alpha * inv, gamma * inv, th, 0.f);
        }
    }
}

// ---------------- attention GEMM v10: all predictable loads hoisted out of the K-step ----------------
// bits preloaded in regs; tab prefetched 1 step ahead in regs; B double-buffered LDS, 1 barrier/step.
// A-gen uses exp(lrelu(x)) = max(exp(x), exp(0.01x)):  P = bit ? max(pA*eb, pG*ed) : 0.
template<int NSTEPS>
__global__ __launch_bounds__(256, 3) void att_gemm(const unsigned long long* __restrict__ bits,
                                                   const float4* __restrict__ rowco,
                                                   const float* __restrict__ tab2f,
                                                   const unsigned short* __restrict__ Bt,  // Whbt [256][4096]
                                                   unsigned short* __restrict__ parth) {
    const int t = threadIdx.x;
    const int bm = blockIdx.x & 31;
    const int bn = (blockIdx.x >> 5) & 1;
    const int ks = blockIdx.x >> 6;
    const int m0 = bm * 128, n0 = bn * 128;
    const int k0 = ks * (NSTEPS * 32);
    __shared__ unsigned short Bs[2][128 * 40];
    const int lane = t & 63, wave = t >> 6;
    const int g = lane >> 4, ml = lane & 15;
    const int srow = t >> 1, skh = (t & 1) * 16;
    const unsigned short* bsrc = Bt + (size_t)(n0 + srow) * 4096 + skh;

    float pA[2], pG[2];
    unsigned long long wpre[2][NSTEPS / 2];
    #pragma unroll
    for (int fm = 0; fm < 2; ++fm) {
        int row = m0 + wave * 32 + fm * 16 + ml;
        float4 rc = rowco[row];
        pA[fm] = rc.x; pG[fm] = rc.y;
        const unsigned long long* brow = bits + (size_t)row * WPR + (k0 >> 6);
        #pragma unroll
        for (int w = 0; w < NSTEPS / 2; ++w) wpre[fm][w] = brow[w];
    }

    float4v acc[2][8];
    #pragma unroll
    for (int i = 0; i < 2; ++i)
        #pragma unroll
        for (int j = 0; j < 8; ++j) acc[i][j] = (float4v){0.f, 0.f, 0.f, 0.f};

    // prologue: stage B step0; prefetch tab step0 to regs
    float4v tq0, tq1, tq2, tq3;
    {
        ushort8v b0 = *(const ushort8v*)&bsrc[k0];
        ushort8v b1 = *(const ushort8v*)&bsrc[k0 + 8];
        const float4v* q = (const float4v*)&tab2f[2 * (k0 + g * 8)];
        tq0 = q[0]; tq1 = q[1]; tq2 = q[2]; tq3 = q[3];
        *(ushort8v*)&Bs[0][srow * 40 + skh]     = b0;
        *(ushort8v*)&Bs[0][srow * 40 + skh + 8] = b1;
    }
    __syncthreads();

    #pragma unroll
    for (int i = 0; i < NSTEPS; ++i) {
        const int kk = k0 + i * 32;
        const int p = i & 1;
        // prefetch next-step B + tab
        ushort8v nb0, nb1;
        float4v nt0, nt1, nt2, nt3;
        if (i + 1 < NSTEPS) {
            nb0 = *(const ushort8v*)&bsrc[kk + 32];
            nb1 = *(const ushort8v*)&bsrc[kk + 40];
            const float4v* q = (const float4v*)&tab2f[2 * (kk + 32 + g * 8)];
            nt0 = q[0]; nt1 = q[1]; nt2 = q[2]; nt3 = q[3];
        }
        // A-gen: pure reg math (bits in regs, tab in regs)
        const int sh = (i & 1) * 32 + g * 8;
        short8 afr[2];
        #pragma unroll
        for (int fm = 0; fm < 2; ++fm) {
            unsigned int wh = (unsigned int)(wpre[fm][i >> 1] >> sh);
            ushort8v af;
            #pragma unroll
            for (int jj = 0; jj < 4; ++jj) {
                float4v v = (jj == 0) ? tq0 : (jj == 1) ? tq1 : (jj == 2) ? tq2 : tq3;
                float x0 = fmaxf(pA[fm] * v[0], pG[fm] * v[1]);
                float x1 = fmaxf(pA[fm] * v[2], pG[fm] * v[3]);
                x0 = ((wh >> (2 * jj)) & 1u)     ? x0 : 0.f;
                x1 = ((wh >> (2 * jj + 1)) & 1u) ? x1 : 0.f;
                union { __hip_bfloat162 b2; unsigned int u; } cv;
                cv.b2 = __float22bfloat162_rn(make_float2(x0, x1));
                ((unsigned int*)&af)[jj] = cv.u;
            }
            afr[fm] = as_s8(af);
        }
        // MFMA from LDS B
        #pragma unroll
        for (int fn = 0; fn < 8; ++fn) {
            short8 b = as_s8(*(const ushort8v*)&Bs[p][(fn * 16 + ml) * 40 + g * 8]);
            acc[0][fn] = __builtin_amdgcn_mfma_f32_16x16x32_bf16(afr[0], b, acc[0][fn], 0, 0, 0);
            acc[1][fn] = __builtin_amdgcn_mfma_f32_16x16x32_bf16(afr[1], b, acc[1][fn], 0, 0, 0);
        }
        // stage next step, single barrier; rotate tab regs
        if (i + 1 < NSTEPS) {
            *(ushort8v*)&Bs[1 - p][srow * 40 + skh]     = nb0;
            *(ushort8v*)&Bs[1 - p][srow * 40 + skh + 8] = nb1;
            __syncthreads();
            tq0 = nt0; tq1 = nt1; tq2 = nt2; tq3 = nt3;
        }
    }

    // permuted coalesced fp16 epilogue: P = ((wave*16+fm*8+fn)*64 + lane)*4 + r
    unsigned short* pbase = parth + ((size_t)ks << 20) + (size_t)(bm * 2 + bn) * 16384;
    #pragma unroll
    for (int fm = 0; fm < 2; ++fm)
        #pragma unroll
        for (int fn = 0; fn < 8; ++fn) {
            ushort4v v4;
            #pragma unroll
            for (int r = 0; r < 4; ++r) {
                __half h = __float2half(acc[fm][fn][r]);
                v4[r] = *(unsigned short*)&h;
            }
            *(ushort4v*)&pbase[((wave * 16 + fm * 8 + fn) * 64 + lane) * 4] = v4;
        }
}

// ---------------- reduce permuted fp16 split-K partials + ELU, coalesced ----------------
template<int NS>
__global__ __launch_bounds__(256) void att_reduce(const unsigned short* __restrict__ parth,
                                                  float* __restrict__ outf,
                                                  unsigned short* __restrict__ hrow) {
    const int flat = (blockIdx.x * 256 + threadIdx.x) * 8;
    float s[8] = {0.f, 0.f, 0.f, 0.f, 0.f, 0.f, 0.f, 0.f};
    #pragma unroll
    for (int sp = 0; sp < NS; ++sp) {
        ushort8v v = *(const ushort8v*)&parth[((size_t)sp << 20) + flat];
        #pragma unroll
        for (int j = 0; j < 8; ++j) {
            unsigned short u = v[j];
            s[j] += __half2float(*(__half*)&u);
        }
    }
    const int tile  = flat >> 14;
    const int inner = flat & 16383;
    const int widx = inner >> 8;
    const int ls   = (inner >> 2) & 63;
    const int bm = tile >> 1, bn = tile & 1;
    const int wavea = widx >> 4, fm = (widx >> 3) & 1, fn = widx & 7;
    const int g = ls >> 4, ml = ls & 15;
    const int row0 = bm * 128 + wavea * 32 + fm * 16 + g * 4;
    const int col  = bn * 128 + fn * 16 + ml;
    #pragma unroll
    for (int r = 0; r < 4; ++r) {
        float x0 = s[r];
        float x1 = s[4 + r];
        x0 = x0 > 0.f ? x0 : (__expf(x0) - 1.f);
        x1 = x1 > 0.f ? x1 : (__expf(x1) - 1.f);
        unsigned int hp = (unsigned int)f2bf(x0) | ((unsigned int)f2bf(x1) << 16);
        *(unsigned int*)&hrow[(size_t)(row0 + r) * 256 + col] = hp;
        if (outf) *(float2*)&outf[(size_t)(row0 + r) * 256 + col] = make_float2(x0, x1);
    }
}

static void launch_att(int SPLIT, const unsigned long long* bits, const float4* rowco,
                       const float* tab2f, const unsigned short* Bt,
                       unsigned short* parth, hipStream_t stream) {
    if (SPLIT == 16) att_gemm<8><<<64 * 16, 256, 0, stream>>>(bits, rowco, tab2f, Bt, parth);
    else             att_gemm<16><<<64 * 8, 256, 0, stream>>>(bits, rowco, tab2f, Bt, parth);
}

static void launch_reduce(int SPLIT, const unsigned short* parth, float* outf,
                          unsigned short* hrow, hipStream_t stream) {
    if (SPLIT == 16) att_reduce<16><<<512, 256, 0, stream>>>(parth, outf, hrow);
    else             att_reduce<8><<<512, 256, 0, stream>>>(parth, outf, hrow);
}

extern "C" void kernel_launch(void* const* d_in, const int* in_sizes, int n_in,
                              void* d_out, int out_size, void* d_ws, size_t ws_size,
                              hipStream_t stream) {
    const float* input = (const float*)d_in[0];
    const int*   adj   = (const int*)d_in[1];
    const float* W0    = (const float*)d_in[2];
    const float* W1    = (const float*)d_in[3];
    const float* a1    = (const float*)d_in[4];
    const float* W2    = (const float*)d_in[5];
    const float* a2    = (const float*)d_in[6];
    const float* W3    = (const float*)d_in[7];
    const float* a3    = (const float*)d_in[8];
    float* out = (float*)d_out;
    char* ws = (char*)d_ws;

    unsigned long long* bits = (unsigned long long*)(ws);                 // 2 MB
    unsigned short* h0   = (unsigned short*)(ws + (2u << 20));            // 2 MB
    unsigned short* h1   = (unsigned short*)(ws + (4u << 20));            // 2 MB
    unsigned short* Whbt = (unsigned short*)(ws + (6u << 20));            // 2 MB
    unsigned short* Wbt  = (unsigned short*)(ws + (8u << 20));            // 512 KB
    float*  f1f2  = (float*)(ws + (9u << 20));                            // 3 layers x 32 KB
    float4* rowco = (float4*)(ws + (10u << 20));                          // 64 KB
    float2* tab2  = (float2*)(ws + (10u << 20) + (256u << 10));           // 32 KB
    unsigned short* parth = (unsigned short*)(ws + (13u << 20));          // 2 MB * SPLIT (fp16)

    const size_t base = 13u << 20;
    int SPLIT = (base + 16u * (2u << 20) <= ws_size) ? 16 : 8;

    float* f1f2_l[3] = { f1f2, f1f2 + 8192, f1f2 + 16384 };

    setup<<<5124, 256, 0, stream>>>(adj, input, W0, W1, W2, W3, bits, h0, Wbt, f1f2);

    // h = input @ W0 -> h1
    proj_gemm<<<512, 256, 0, stream>>>(h0, Wbt + 0 * 65536, nullptr, nullptr, nullptr, h1);

    // layer 1
    proj_gemm<<<512, 256, 0, stream>>>(h1, Wbt + 1 * 65536, a1, f1f2_l[0], Whbt, nullptr);
    rowcoef<<<512, 256, 0, stream>>>(bits, f1f2_l[0], rowco, tab2);
    launch_att(SPLIT, bits, rowco, (const float*)tab2, Whbt, parth, stream);
    launch_reduce(SPLIT, parth, nullptr, h0, stream);

    // layer 2
    proj_gemm<<<512, 256, 0, stream>>>(h0, Wbt + 2 * 65536, a2, f1f2_l[1], Whbt, nullptr);
    rowcoef<<<512, 256, 0, stream>>>(bits, f1f2_l[1], rowco, tab2);
    launch_att(SPLIT, bits, rowco, (const float*)tab2, Whbt, parth, stream);
    launch_reduce(SPLIT, parth, nullptr, h1, stream);

    // layer 3
    proj_gemm<<<512, 256, 0, stream>>>(h1, Wbt + 3 * 65536, a3, f1f2_l[2], Whbt, nullptr);
    rowcoef<<<512, 256, 0, stream>>>(bits, f1f2_l[2], rowco, tab2);
    launch_att(SPLIT, bits, rowco, (const float*)tab2, Whbt, parth, stream);
    launch_reduce(SPLIT, parth, out, h0, stream);
}